// Round 6
// baseline (1756.072 us; speedup 1.0000x reference)
//
#include <hip/hip_runtime.h>
#include <hip/hip_bf16.h>
#include <math.h>

// ---------------------------------------------------------------------------
// GCN 2-layer: out = log_softmax( Ahat @ relu(Ahat @ (X W1) + b1) @ W2 + b2 )
// Round 6: edge-parallel bucket-resident aggregation (LDS fp32 accumulators,
// ds atomics). build_k (in-LDS counting sort) deleted; aggs consume the
// bucket-partitioned pairs directly. deg_k produces dinv only.
// ---------------------------------------------------------------------------

#define DIM 32
#define NCLS 40
#define F_IN 512
#define BSH 7            // bucket = dst >> 7 (128 nodes/bucket)
#define NPB 128          // nodes per bucket
#define EPB 4096         // edges per block in hist/part

// ---- bf16 helpers (RNE pack, exact unpack) ----
__device__ __forceinline__ unsigned int bf16rne(float x) {
    unsigned int u = __float_as_uint(x);
    return (u + 0x7fffu + ((u >> 16) & 1u)) >> 16;
}
__device__ __forceinline__ unsigned int packpair(float lo, float hi) {
    return bf16rne(lo) | (bf16rne(hi) << 16);
}
__device__ __forceinline__ void unpack8(uint4 u, float* f) {
    f[0] = __uint_as_float(u.x << 16);
    f[1] = __uint_as_float(u.x & 0xffff0000u);
    f[2] = __uint_as_float(u.y << 16);
    f[3] = __uint_as_float(u.y & 0xffff0000u);
    f[4] = __uint_as_float(u.z << 16);
    f[5] = __uint_as_float(u.z & 0xffff0000u);
    f[6] = __uint_as_float(u.w << 16);
    f[7] = __uint_as_float(u.w & 0xffff0000u);
}

// ---------------- K1: bucket histogram (LDS-aggregated) ----------------
__global__ __launch_bounds__(256) void hist_k(const int* __restrict__ dst,
                                              int* __restrict__ gh, int E) {
    __shared__ int h[1024];
    int tid = threadIdx.x;
#pragma unroll
    for (int s = 0; s < 4; ++s) h[tid + 256 * s] = 0;
    __syncthreads();
    int base = blockIdx.x * EPB;
#pragma unroll 4
    for (int k = 0; k < EPB / 256; ++k) {
        int e = base + k * 256 + tid;
        if (e < E) atomicAdd(&h[dst[e] >> BSH], 1);
    }
    __syncthreads();
#pragma unroll
    for (int s = 0; s < 4; ++s) {
        int b = tid + 256 * s;
        if (h[b]) atomicAdd(&gh[b], h[b]);
    }
}

// ---------------- K2: scan buckets -> base + cursor (1 block, nbk<=1024) ---
__global__ __launch_bounds__(1024) void scanb_k(const int* __restrict__ gh,
                                                int* __restrict__ bbase,
                                                int* __restrict__ gcur, int nbk) {
    __shared__ int sh[1024];
    int t = threadIdx.x;
    int c = (t < nbk) ? gh[t] : 0;
    sh[t] = c;
    __syncthreads();
    for (int off = 1; off < 1024; off <<= 1) {
        int v = sh[t];
        if (t >= off) v += sh[t - off];
        __syncthreads();
        sh[t] = v;
        __syncthreads();
    }
    int excl = sh[t] - c;
    if (t < nbk) { bbase[t] = excl; gcur[t] = excl; }
    if (t == 0) bbase[nbk] = sh[1023];   // = E
}

// ---------------- K3: partition into buckets, packed payload --------------
// payload = ((dst & 127) << 17) | src   (src < 2^17)
__global__ __launch_bounds__(256) void part_k(const int* __restrict__ src,
                                              const int* __restrict__ dst,
                                              int* __restrict__ gcur,
                                              int* __restrict__ pairs, int E) {
    __shared__ int st[EPB];     // staged dst values
    __shared__ int h[1024];
    __shared__ int hb[1024];
    int tid = threadIdx.x;
#pragma unroll
    for (int s = 0; s < 4; ++s) h[tid + 256 * s] = 0;
    __syncthreads();
    int base = blockIdx.x * EPB;
#pragma unroll 4
    for (int k = 0; k < EPB / 256; ++k) {
        int e = base + k * 256 + tid;
        if (e < E) {
            int d = dst[e];
            st[k * 256 + tid] = d;
            atomicAdd(&h[d >> BSH], 1);
        }
    }
    __syncthreads();
    for (int b = tid; b < 1024; b += 256) {
        int cnt = h[b];
        hb[b] = cnt ? atomicAdd(&gcur[b], cnt) : 0;
        h[b] = 0;  // reuse as running offset
    }
    __syncthreads();
#pragma unroll 4
    for (int k = 0; k < EPB / 256; ++k) {
        int e = base + k * 256 + tid;
        if (e < E) {
            int d = st[k * 256 + tid];
            int b = d >> BSH;
            int r = atomicAdd(&h[b], 1);
            pairs[hb[b] + r] = ((d & (NPB - 1)) << 17) | src[e];
        }
    }
}

// ---------------- K4: per-bucket degree -> dinv (no sort) ------------------
__global__ __launch_bounds__(256) void deg_k(const int* __restrict__ pairs,
                                             const int* __restrict__ bbase,
                                             float* __restrict__ dinv, int n) {
    __shared__ int cnt[NPB];
    int tid = threadIdx.x;
    int b = blockIdx.x;
    int lo = bbase[b], hi = bbase[b + 1];
    if (tid < NPB) cnt[tid] = 0;
    __syncthreads();
    for (int i = lo + tid; i < hi; i += 256)
        atomicAdd(&cnt[pairs[i] >> 17], 1);
    __syncthreads();
    int v = (b << BSH) + tid;
    if (tid < NPB && v < n) dinv[v] = rsqrtf((float)(cnt[tid] + 1));
}

// ---------------- GEMM1: 4x4 register micro-tile (r5, unchanged) -----------
#define GR 128
__global__ __launch_bounds__(256) void gemm1_k(const float* __restrict__ x,
                                               const float* __restrict__ W1,
                                               const float* __restrict__ dinv,
                                               unsigned short* __restrict__ xwp, int n) {
    __shared__ float xs[32 * GR];   // [kk][row], 16 KB
    __shared__ float ws[32 * 32];   // [kk][col], 4 KB
    int tid = threadIdx.x;
    int base = blockIdx.x * GR;
    int rg = tid & 31;        // rows 4rg..4rg+3
    int cg = tid >> 5;        // cols 4cg..4cg+3
    float acc[4][4];
#pragma unroll
    for (int i = 0; i < 4; ++i)
#pragma unroll
        for (int j = 0; j < 4; ++j) acc[i][j] = 0.f;

    int lr = tid >> 1;        // staging row 0..127
    int lq = tid & 1;         // k half
    int grow = base + lr;
    if (grow >= n) grow = n - 1;
    const float* xrow = x + (size_t)grow * F_IN;
    int wk = tid >> 3;        // 0..31
    int wc = tid & 7;         // 0..7

    for (int k0 = 0; k0 < F_IN; k0 += 32) {
        float4 a[4];
#pragma unroll
        for (int j = 0; j < 4; ++j)
            a[j] = *(const float4*)(xrow + k0 + lq * 16 + j * 4);
        float4 wv = *(const float4*)(W1 + (size_t)(k0 + wk) * DIM + wc * 4);
        __syncthreads();
#pragma unroll
        for (int j = 0; j < 4; ++j) {
            xs[(lq * 16 + j * 4 + 0) * GR + lr] = a[j].x;
            xs[(lq * 16 + j * 4 + 1) * GR + lr] = a[j].y;
            xs[(lq * 16 + j * 4 + 2) * GR + lr] = a[j].z;
            xs[(lq * 16 + j * 4 + 3) * GR + lr] = a[j].w;
        }
        *(float4*)&ws[wk * 32 + wc * 4] = wv;
        __syncthreads();
#pragma unroll 8
        for (int kk = 0; kk < 32; ++kk) {
            float4 xv = *(const float4*)&xs[kk * GR + rg * 4];
            float4 wv2 = *(const float4*)&ws[kk * 32 + cg * 4];
            acc[0][0] = fmaf(xv.x, wv2.x, acc[0][0]);
            acc[0][1] = fmaf(xv.x, wv2.y, acc[0][1]);
            acc[0][2] = fmaf(xv.x, wv2.z, acc[0][2]);
            acc[0][3] = fmaf(xv.x, wv2.w, acc[0][3]);
            acc[1][0] = fmaf(xv.y, wv2.x, acc[1][0]);
            acc[1][1] = fmaf(xv.y, wv2.y, acc[1][1]);
            acc[1][2] = fmaf(xv.y, wv2.z, acc[1][2]);
            acc[1][3] = fmaf(xv.y, wv2.w, acc[1][3]);
            acc[2][0] = fmaf(xv.z, wv2.x, acc[2][0]);
            acc[2][1] = fmaf(xv.z, wv2.y, acc[2][1]);
            acc[2][2] = fmaf(xv.z, wv2.z, acc[2][2]);
            acc[2][3] = fmaf(xv.z, wv2.w, acc[2][3]);
            acc[3][0] = fmaf(xv.w, wv2.x, acc[3][0]);
            acc[3][1] = fmaf(xv.w, wv2.y, acc[3][1]);
            acc[3][2] = fmaf(xv.w, wv2.z, acc[3][2]);
            acc[3][3] = fmaf(xv.w, wv2.w, acc[3][3]);
        }
    }
#pragma unroll
    for (int i = 0; i < 4; ++i) {
        int row = base + rg * 4 + i;
        if (row < n) {
            float dv = dinv[row];
            uint2 o;
            o.x = packpair(acc[i][0] * dv, acc[i][1] * dv);
            o.y = packpair(acc[i][2] * dv, acc[i][3] * dv);
            *(uint2*)(xwp + (size_t)row * DIM + cg * 4) = o;
        }
    }
}

// ---- shared edge-accumulation body: acc[128][33] fp32, LDS atomics --------
// group = 4 lanes per edge, lane f8 owns 8 feats.
#define EDGE_ACC_BODY(F_, pairs_, lo_, hi_)                                     \
    {                                                                           \
        int g = tid >> 2, f8 = tid & 3;                                         \
        int i = lo_ + g;                                                        \
        for (; i + 192 < hi_; i += 256) {                                       \
            int p0 = pairs_[i], p1 = pairs_[i + 64];                            \
            int p2 = pairs_[i + 128], p3 = pairs_[i + 192];                     \
            uint4 r0 = F_[(size_t)(p0 & 0x1FFFF) * 4 + f8];                     \
            uint4 r1 = F_[(size_t)(p1 & 0x1FFFF) * 4 + f8];                     \
            uint4 r2 = F_[(size_t)(p2 & 0x1FFFF) * 4 + f8];                     \
            uint4 r3 = F_[(size_t)(p3 & 0x1FFFF) * 4 + f8];                     \
            float t0[8], t1[8], t2[8], t3[8];                                   \
            unpack8(r0, t0); unpack8(r1, t1);                                   \
            unpack8(r2, t2); unpack8(r3, t3);                                   \
            float* a0 = &acc[(p0 >> 17) * 33 + f8 * 8];                         \
            float* a1 = &acc[(p1 >> 17) * 33 + f8 * 8];                         \
            float* a2p = &acc[(p2 >> 17) * 33 + f8 * 8];                        \
            float* a3 = &acc[(p3 >> 17) * 33 + f8 * 8];                         \
            _Pragma("unroll")                                                   \
            for (int j = 0; j < 8; ++j) atomicAdd(&a0[j], t0[j]);               \
            _Pragma("unroll")                                                   \
            for (int j = 0; j < 8; ++j) atomicAdd(&a1[j], t1[j]);               \
            _Pragma("unroll")                                                   \
            for (int j = 0; j < 8; ++j) atomicAdd(&a2p[j], t2[j]);              \
            _Pragma("unroll")                                                   \
            for (int j = 0; j < 8; ++j) atomicAdd(&a3[j], t3[j]);               \
        }                                                                       \
        for (; i < hi_; i += 64) {                                              \
            int p = pairs_[i];                                                  \
            uint4 r = F_[(size_t)(p & 0x1FFFF) * 4 + f8];                       \
            float t0[8];                                                        \
            unpack8(r, t0);                                                     \
            float* a0 = &acc[(p >> 17) * 33 + f8 * 8];                          \
            _Pragma("unroll")                                                   \
            for (int j = 0; j < 8; ++j) atomicAdd(&a0[j], t0[j]);               \
        }                                                                       \
    }

// ---------------- agg1: out = bf16( relu(acc*dinv + b1) * dinv ) -----------
__global__ __launch_bounds__(256) void eagg1_k(const uint4* __restrict__ F,
                                               const int* __restrict__ pairs,
                                               const int* __restrict__ bbase,
                                               const float* __restrict__ dinv,
                                               const float* __restrict__ bias,
                                               uint4* __restrict__ out, int n) {
    __shared__ float acc[NPB * 33];     // 16.9 KB
    int tid = threadIdx.x;
    int b = blockIdx.x;
    int vb = b << BSH;
    int nl = tid >> 1, half = tid & 1;
    int v = vb + nl;
    if (v < n) {        // self term (features pre-scaled by dinv)
        uint4 r0 = F[(size_t)v * 4 + half * 2];
        uint4 r1 = F[(size_t)v * 4 + half * 2 + 1];
        float tmp[8];
        unpack8(r0, tmp);
#pragma unroll
        for (int j = 0; j < 8; ++j) acc[nl * 33 + half * 16 + j] = tmp[j];
        unpack8(r1, tmp);
#pragma unroll
        for (int j = 0; j < 8; ++j) acc[nl * 33 + half * 16 + 8 + j] = tmp[j];
    }
    __syncthreads();
    int lo = bbase[b], hi = bbase[b + 1];
    EDGE_ACC_BODY(F, pairs, lo, hi)
    __syncthreads();
    if (v < n) {
        float dv = dinv[v];
        float4 bq0 = *(const float4*)(bias + half * 16);
        float4 bq1 = *(const float4*)(bias + half * 16 + 4);
        float4 bq2 = *(const float4*)(bias + half * 16 + 8);
        float4 bq3 = *(const float4*)(bias + half * 16 + 12);
        float bb[16] = {bq0.x, bq0.y, bq0.z, bq0.w, bq1.x, bq1.y, bq1.z, bq1.w,
                        bq2.x, bq2.y, bq2.z, bq2.w, bq3.x, bq3.y, bq3.z, bq3.w};
        float r[16];
#pragma unroll
        for (int j = 0; j < 16; ++j)
            r[j] = fmaxf(acc[nl * 33 + half * 16 + j] * dv + bb[j], 0.f) * dv;
        uint4 o0, o1;
        o0.x = packpair(r[0], r[1]);  o0.y = packpair(r[2], r[3]);
        o0.z = packpair(r[4], r[5]);  o0.w = packpair(r[6], r[7]);
        o1.x = packpair(r[8], r[9]);  o1.y = packpair(r[10], r[11]);
        o1.z = packpair(r[12], r[13]); o1.w = packpair(r[14], r[15]);
        out[(size_t)v * 4 + half * 2] = o0;
        out[(size_t)v * 4 + half * 2 + 1] = o1;
    }
}

// ---------------- agg2 + (a2 @ W2 + b2) + log_softmax, fused ---------------
__global__ __launch_bounds__(256) void eagg2f_k(const uint4* __restrict__ F,
                                                const int* __restrict__ pairs,
                                                const int* __restrict__ bbase,
                                                const float* __restrict__ dinv,
                                                const float* __restrict__ W2,
                                                const float* __restrict__ b2,
                                                float* __restrict__ out, int n) {
    __shared__ float acc[NPB * 33];     // 16.9 KB
    __shared__ float w2s[DIM * NCLS];   // 5 KB
    __shared__ float b2s[NCLS];
    int tid = threadIdx.x;
    int b = blockIdx.x;
    int vb = b << BSH;
    for (int i = tid; i < DIM * NCLS; i += 256) w2s[i] = W2[i];
    if (tid < NCLS) b2s[tid] = b2[tid];
    int nl = tid >> 1, half = tid & 1;
    int v = vb + nl;
    if (v < n) {        // self term
        uint4 r0 = F[(size_t)v * 4 + half * 2];
        uint4 r1 = F[(size_t)v * 4 + half * 2 + 1];
        float tmp[8];
        unpack8(r0, tmp);
#pragma unroll
        for (int j = 0; j < 8; ++j) acc[nl * 33 + half * 16 + j] = tmp[j];
        unpack8(r1, tmp);
#pragma unroll
        for (int j = 0; j < 8; ++j) acc[nl * 33 + half * 16 + 8 + j] = tmp[j];
    }
    __syncthreads();
    int lo = bbase[b], hi = bbase[b + 1];
    EDGE_ACC_BODY(F, pairs, lo, hi)
    __syncthreads();

    // epilogue: classes half*20 .. +19 for node nl
    float dv = dinv[(v < n) ? v : (n - 1)];
    int c0 = half * 20;
    float lg[20];
#pragma unroll
    for (int c = 0; c < 20; ++c) lg[c] = b2s[c0 + c];
#pragma unroll 4
    for (int k = 0; k < DIM; ++k) {
        float a = acc[nl * 33 + k] * dv;
        const float* wr = &w2s[k * NCLS + c0];
#pragma unroll
        for (int c = 0; c < 20; ++c) lg[c] = fmaf(a, wr[c], lg[c]);
    }
    float m = lg[0];
#pragma unroll
    for (int c = 1; c < 20; ++c) m = fmaxf(m, lg[c]);
    m = fmaxf(m, __shfl_xor(m, 1));
    float ssum = 0.f;
#pragma unroll
    for (int c = 0; c < 20; ++c) ssum += __expf(lg[c] - m);
    ssum += __shfl_xor(ssum, 1);
    float lse = m + __logf(ssum);
    if (v < n) {
        float* o = out + (size_t)v * NCLS + c0;
#pragma unroll
        for (int c = 0; c < 5; ++c) {
            float4 q;
            q.x = lg[c * 4] - lse;     q.y = lg[c * 4 + 1] - lse;
            q.z = lg[c * 4 + 2] - lse; q.w = lg[c * 4 + 3] - lse;
            *(float4*)(o + c * 4) = q;
        }
    }
}

// ---------------------------------------------------------------------------
extern "C" void kernel_launch(void* const* d_in, const int* in_sizes, int n_in,
                              void* d_out, int out_size, void* d_ws, size_t ws_size,
                              hipStream_t stream) {
    const float* x  = (const float*)d_in[0];
    const int*   ei = (const int*)d_in[1];
    const float* W1 = (const float*)d_in[2];
    const float* b1 = (const float*)d_in[3];
    const float* W2 = (const float*)d_in[4];
    const float* b2 = (const float*)d_in[5];
    float* out = (float*)d_out;

    int n = in_sizes[0] / F_IN;   // 100000
    int E = in_sizes[1] / 2;      // 3200000
    const int* src = ei;
    const int* dst = ei + E;
    int nbk = (n + NPB - 1) >> BSH;   // 782 (<=1024)

    // workspace layout (256B aligned)
    char* w = (char*)d_ws;
    size_t off = 0;
    auto alloc = [&](size_t bytes) -> void* {
        void* p = w + off;
        off += (bytes + 255) & ~(size_t)255;
        return p;
    };
    int*            pairs = (int*)alloc((size_t)E * 4);          // 12.8 MB
    unsigned short* xwp   = (unsigned short*)alloc((size_t)n * DIM * 2);
    unsigned short* hts   = (unsigned short*)alloc((size_t)n * DIM * 2);
    float*          dinv  = (float*)alloc((size_t)n * 4);
    int*            gh    = (int*)alloc(1024 * 4);
    int*            bbase = (int*)alloc(1025 * 4);
    int*            gcur  = (int*)alloc(1024 * 4);
    (void)ws_size;

    hipMemsetAsync(gh, 0, 1024 * 4, stream);

    int nebk = (E + EPB - 1) / EPB;   // 782
    hist_k <<<nebk, 256, 0, stream>>>(dst, gh, E);
    scanb_k<<<1, 1024, 0, stream>>>(gh, bbase, gcur, nbk);
    part_k <<<nebk, 256, 0, stream>>>(src, dst, gcur, pairs, E);
    deg_k  <<<nbk, 256, 0, stream>>>(pairs, bbase, dinv, n);

    gemm1_k<<<(n + GR - 1) / GR, 256, 0, stream>>>(x, W1, dinv, xwp, n);
    eagg1_k<<<nbk, 256, 0, stream>>>(
        (const uint4*)xwp, pairs, bbase, dinv, b1, (uint4*)hts, n);
    eagg2f_k<<<nbk, 256, 0, stream>>>(
        (const uint4*)hts, pairs, bbase, dinv, W2, b2, out, n);
}

// Round 7
// 514.962 us; speedup vs baseline: 3.4101x; 3.4101x over previous
//
#include <hip/hip_runtime.h>
#include <hip/hip_bf16.h>
#include <math.h>

// ---------------------------------------------------------------------------
// GCN 2-layer: out = log_softmax( Ahat @ relu(Ahat @ (X W1) + b1) @ W2 + b2 )
// Round 7: round-5 structure (best: 523.7us) + per-node src-region sort in
// build_k (16-bin counting sort by src>>13) so the agg gathers sweep the
// feature table in lockstep -> L2-resident working set.
// Round 6's LDS-atomic edge-parallel agg REVERTED (ds_add RMW serialization:
// VALUBusy 1.2%, 677us/dispatch).
// ---------------------------------------------------------------------------

#define DIM 32
#define NCLS 40
#define F_IN 512
#define BSH 8            // bucket = dst >> 8 (256 nodes/bucket)
#define EPB 8192         // edges per block in hist/part
#define LMAX 9216        // max edges per bucket (mean 8192 + 11 sigma)

// ---- bf16 helpers (RNE pack, exact unpack) ----
__device__ __forceinline__ unsigned int bf16rne(float x) {
    unsigned int u = __float_as_uint(x);
    return (u + 0x7fffu + ((u >> 16) & 1u)) >> 16;
}
__device__ __forceinline__ unsigned int packpair(float lo, float hi) {
    return bf16rne(lo) | (bf16rne(hi) << 16);
}
__device__ __forceinline__ void unpack8(uint4 u, float* f) {
    f[0] = __uint_as_float(u.x << 16);
    f[1] = __uint_as_float(u.x & 0xffff0000u);
    f[2] = __uint_as_float(u.y << 16);
    f[3] = __uint_as_float(u.y & 0xffff0000u);
    f[4] = __uint_as_float(u.z << 16);
    f[5] = __uint_as_float(u.z & 0xffff0000u);
    f[6] = __uint_as_float(u.w << 16);
    f[7] = __uint_as_float(u.w & 0xffff0000u);
}

// ---------------- K1: bucket histogram (LDS-aggregated) ----------------
__global__ __launch_bounds__(256) void hist_k(const int* __restrict__ dst,
                                              int* __restrict__ gh, int E, int nbk) {
    __shared__ int h[512];
    int tid = threadIdx.x;
    h[tid] = 0; h[tid + 256] = 0;
    __syncthreads();
    int base = blockIdx.x * EPB;
#pragma unroll 4
    for (int k = 0; k < EPB / 256; ++k) {
        int e = base + k * 256 + tid;
        if (e < E) atomicAdd(&h[dst[e] >> BSH], 1);
    }
    __syncthreads();
    if (h[tid]) atomicAdd(&gh[tid], h[tid]);
    if (h[tid + 256]) atomicAdd(&gh[tid + 256], h[tid + 256]);
}

// ---------------- K2: scan buckets -> base + cursor (1 block, nbk<=512) ----
__global__ __launch_bounds__(512) void scanb_k(const int* __restrict__ gh,
                                               int* __restrict__ bbase,
                                               int* __restrict__ gcur, int nbk) {
    __shared__ int sh[512];
    int t = threadIdx.x;
    int c = (t < nbk) ? gh[t] : 0;
    sh[t] = c;
    __syncthreads();
    for (int off = 1; off < 512; off <<= 1) {
        int v = sh[t];
        if (t >= off) v += sh[t - off];
        __syncthreads();
        sh[t] = v;
        __syncthreads();
    }
    int excl = sh[t] - c;
    if (t < nbk) { bbase[t] = excl; gcur[t] = excl; }
    if (t == 0) bbase[nbk] = sh[511];   // = E
}

// ---------------- K3: partition into buckets, packed 25-bit payload -------
__global__ __launch_bounds__(256) void part_k(const int* __restrict__ src,
                                              const int* __restrict__ dst,
                                              int* __restrict__ gcur,
                                              int* __restrict__ pairs, int E) {
    __shared__ int st[EPB];     // staged dst values
    __shared__ int h[512];
    __shared__ int hb[512];
    int tid = threadIdx.x;
    h[tid] = 0; h[tid + 256] = 0;
    __syncthreads();
    int base = blockIdx.x * EPB;
#pragma unroll 4
    for (int k = 0; k < EPB / 256; ++k) {
        int e = base + k * 256 + tid;
        if (e < E) {
            int d = dst[e];
            st[k * 256 + tid] = d;
            atomicAdd(&h[d >> BSH], 1);
        }
    }
    __syncthreads();
    for (int b = tid; b < 512; b += 256) {
        int cnt = h[b];
        hb[b] = cnt ? atomicAdd(&gcur[b], cnt) : 0;
        h[b] = 0;  // reuse as running offset
    }
    __syncthreads();
#pragma unroll 4
    for (int k = 0; k < EPB / 256; ++k) {
        int e = base + k * 256 + tid;
        if (e < E) {
            int d = st[k * 256 + tid];
            int b = d >> BSH;
            int r = atomicAdd(&h[b], 1);
            pairs[hb[b] + r] = ((d & 255) << 17) | src[e];   // src < 2^17
        }
    }
}

// ---------------- K4: per-bucket CSR build + per-node src-region sort ------
// Counting sort by dst (as r5) into LDS, then each node's list is counting-
// sorted by src>>13 (16 regions) so agg-loop iteration i touches a narrow
// src band across all waves -> L2-resident gathers.
__global__ __launch_bounds__(256) void build_k(const int* __restrict__ pairs,
                                               const int* __restrict__ bbase,
                                               int* __restrict__ rowptr,
                                               int* __restrict__ csr,
                                               float* __restrict__ dinv,
                                               int n, int nbk, int E) {
    __shared__ int lcsr[LMAX];           // 36.9 KB
    __shared__ int bins[256 * 17];       // 17.4 KB, stride 17 vs bank conflicts
    __shared__ int cnt[256];
    __shared__ int sc[256];
    __shared__ int cur[256];
    int tid = threadIdx.x;
    int b = blockIdx.x;
    int lo = bbase[b], hi = bbase[b + 1];
    int cb = hi - lo; if (cb > LMAX) cb = LMAX;   // statistically never clamps
    cnt[tid] = 0;
    __syncthreads();
    const int* Pb = pairs + lo;
    for (int i = tid; i < cb; i += 256)
        atomicAdd(&cnt[Pb[i] >> 17], 1);
    __syncthreads();
    int c = cnt[tid];
    sc[tid] = c;
    __syncthreads();
    for (int off = 1; off < 256; off <<= 1) {
        int v = sc[tid];
        if (tid >= off) v += sc[tid - off];
        __syncthreads();
        sc[tid] = v;
        __syncthreads();
    }
    int excl = sc[tid] - c;
    int v = (b << BSH) + tid;
    if (v < n) {
        rowptr[v] = lo + excl;
        dinv[v] = rsqrtf((float)(c + 1));   // +1 self loop
    }
    cur[tid] = excl;                        // bucket-local cursor
    __syncthreads();
    for (int i = tid; i < cb; i += 256) {
        int p = Pb[i];
        int pos = atomicAdd(&cur[p >> 17], 1);
        lcsr[pos] = p & 0x1FFFF;
    }
    __syncthreads();
    // per-node 16-bin counting sort by src>>13 (one thread per node)
    {
        int* mb = &bins[tid * 17];
        int s = excl, e = excl + c;
#pragma unroll
        for (int k = 0; k < 16; ++k) mb[k] = 0;
        for (int i = s; i < e; ++i) ++mb[lcsr[i] >> 13];
        int run = s;
#pragma unroll
        for (int k = 0; k < 16; ++k) { int q = mb[k]; mb[k] = run; run += q; }
        for (int i = s; i < e; ++i) {
            int val = lcsr[i];
            int k = val >> 13;
            int pos = mb[k]++;
            csr[lo + pos] = val;
        }
    }
    if (b == 0 && tid == 0) rowptr[n] = E;
}

// ---------------- GEMM1: 4x4 register micro-tile (r5, unchanged) -----------
#define GR 128
__global__ __launch_bounds__(256) void gemm1_k(const float* __restrict__ x,
                                               const float* __restrict__ W1,
                                               const float* __restrict__ dinv,
                                               unsigned short* __restrict__ xwp, int n) {
    __shared__ float xs[32 * GR];   // [kk][row], 16 KB
    __shared__ float ws[32 * 32];   // [kk][col], 4 KB
    int tid = threadIdx.x;
    int base = blockIdx.x * GR;
    int rg = tid & 31;        // rows 4rg..4rg+3
    int cg = tid >> 5;        // cols 4cg..4cg+3
    float acc[4][4];
#pragma unroll
    for (int i = 0; i < 4; ++i)
#pragma unroll
        for (int j = 0; j < 4; ++j) acc[i][j] = 0.f;

    int lr = tid >> 1;        // staging row 0..127
    int lq = tid & 1;         // k half
    int grow = base + lr;
    if (grow >= n) grow = n - 1;
    const float* xrow = x + (size_t)grow * F_IN;
    int wk = tid >> 3;        // 0..31
    int wc = tid & 7;         // 0..7

    for (int k0 = 0; k0 < F_IN; k0 += 32) {
        float4 a[4];
#pragma unroll
        for (int j = 0; j < 4; ++j)
            a[j] = *(const float4*)(xrow + k0 + lq * 16 + j * 4);
        float4 wv = *(const float4*)(W1 + (size_t)(k0 + wk) * DIM + wc * 4);
        __syncthreads();
#pragma unroll
        for (int j = 0; j < 4; ++j) {
            xs[(lq * 16 + j * 4 + 0) * GR + lr] = a[j].x;
            xs[(lq * 16 + j * 4 + 1) * GR + lr] = a[j].y;
            xs[(lq * 16 + j * 4 + 2) * GR + lr] = a[j].z;
            xs[(lq * 16 + j * 4 + 3) * GR + lr] = a[j].w;
        }
        *(float4*)&ws[wk * 32 + wc * 4] = wv;
        __syncthreads();
#pragma unroll 8
        for (int kk = 0; kk < 32; ++kk) {
            float4 xv = *(const float4*)&xs[kk * GR + rg * 4];
            float4 wv2 = *(const float4*)&ws[kk * 32 + cg * 4];
            acc[0][0] = fmaf(xv.x, wv2.x, acc[0][0]);
            acc[0][1] = fmaf(xv.x, wv2.y, acc[0][1]);
            acc[0][2] = fmaf(xv.x, wv2.z, acc[0][2]);
            acc[0][3] = fmaf(xv.x, wv2.w, acc[0][3]);
            acc[1][0] = fmaf(xv.y, wv2.x, acc[1][0]);
            acc[1][1] = fmaf(xv.y, wv2.y, acc[1][1]);
            acc[1][2] = fmaf(xv.y, wv2.z, acc[1][2]);
            acc[1][3] = fmaf(xv.y, wv2.w, acc[1][3]);
            acc[2][0] = fmaf(xv.z, wv2.x, acc[2][0]);
            acc[2][1] = fmaf(xv.z, wv2.y, acc[2][1]);
            acc[2][2] = fmaf(xv.z, wv2.z, acc[2][2]);
            acc[2][3] = fmaf(xv.z, wv2.w, acc[2][3]);
            acc[3][0] = fmaf(xv.w, wv2.x, acc[3][0]);
            acc[3][1] = fmaf(xv.w, wv2.y, acc[3][1]);
            acc[3][2] = fmaf(xv.w, wv2.z, acc[3][2]);
            acc[3][3] = fmaf(xv.w, wv2.w, acc[3][3]);
        }
    }
#pragma unroll
    for (int i = 0; i < 4; ++i) {
        int row = base + rg * 4 + i;
        if (row < n) {
            float dv = dinv[row];
            uint2 o;
            o.x = packpair(acc[i][0] * dv, acc[i][1] * dv);
            o.y = packpair(acc[i][2] * dv, acc[i][3] * dv);
            *(uint2*)(xwp + (size_t)row * DIM + cg * 4) = o;
        }
    }
}

// ---------------- agg1: hts = bf16( relu(agg*dinv + b1) * dinv ) ----------
__global__ __launch_bounds__(256) void agg1_k(const uint4* __restrict__ F,
                                              const int* __restrict__ rowptr,
                                              const int* __restrict__ csr,
                                              const float* __restrict__ dinv,
                                              const float* __restrict__ bias,
                                              uint4* __restrict__ out, int n) {
    int t = blockIdx.x * 256 + threadIdx.x;
    int v = t >> 2;
    int f8 = t & 3;
    if (v >= n) return;
    float s[8], tmp[8];
    unpack8(F[(size_t)v * 4 + f8], s);   // self-loop (already *dinv)
    int e = rowptr[v];
    int end = rowptr[v + 1];
    for (; e + 3 < end; e += 4) {
        uint4 ua = F[(size_t)csr[e] * 4 + f8];
        uint4 ub = F[(size_t)csr[e + 1] * 4 + f8];
        uint4 uc = F[(size_t)csr[e + 2] * 4 + f8];
        uint4 ud = F[(size_t)csr[e + 3] * 4 + f8];
        unpack8(ua, tmp);
#pragma unroll
        for (int j = 0; j < 8; ++j) s[j] += tmp[j];
        unpack8(ub, tmp);
#pragma unroll
        for (int j = 0; j < 8; ++j) s[j] += tmp[j];
        unpack8(uc, tmp);
#pragma unroll
        for (int j = 0; j < 8; ++j) s[j] += tmp[j];
        unpack8(ud, tmp);
#pragma unroll
        for (int j = 0; j < 8; ++j) s[j] += tmp[j];
    }
    for (; e < end; ++e) {
        unpack8(F[(size_t)csr[e] * 4 + f8], tmp);
#pragma unroll
        for (int j = 0; j < 8; ++j) s[j] += tmp[j];
    }
    float dv = dinv[v];
    float4 b0 = *(const float4*)(bias + f8 * 8);
    float4 b1 = *(const float4*)(bias + f8 * 8 + 4);
    float bb[8] = {b0.x, b0.y, b0.z, b0.w, b1.x, b1.y, b1.z, b1.w};
    float r[8];
#pragma unroll
    for (int j = 0; j < 8; ++j) r[j] = fmaxf(s[j] * dv + bb[j], 0.f) * dv;
    uint4 o;
    o.x = packpair(r[0], r[1]);
    o.y = packpair(r[2], r[3]);
    o.z = packpair(r[4], r[5]);
    o.w = packpair(r[6], r[7]);
    out[(size_t)v * 4 + f8] = o;
}

// ---------------- fused agg2 + (a2 @ W2 + b2) + log_softmax ----------------
__global__ __launch_bounds__(256) void agg2final_k(const uint4* __restrict__ F,
                                                   const int* __restrict__ rowptr,
                                                   const int* __restrict__ csr,
                                                   const float* __restrict__ dinv,
                                                   const float* __restrict__ W2,
                                                   const float* __restrict__ b2,
                                                   float* __restrict__ out, int n) {
    __shared__ float w2s[DIM * NCLS];   // 1280 floats
    __shared__ float b2s[NCLS];
    __shared__ float a2s[64 * 33];      // 64 nodes x 32 feats, pad 33
    int tid = threadIdx.x;
    for (int i = tid; i < DIM * NCLS; i += 256) w2s[i] = W2[i];
    if (tid < NCLS) b2s[tid] = b2[tid];

    int nl = tid >> 2;       // node-local 0..63
    int f8 = tid & 3;
    int v = blockIdx.x * 64 + nl;
    if (v < n) {
        float s[8], tmp[8];
        unpack8(F[(size_t)v * 4 + f8], s);
        int e = rowptr[v];
        int end = rowptr[v + 1];
        for (; e + 3 < end; e += 4) {
            uint4 ua = F[(size_t)csr[e] * 4 + f8];
            uint4 ub = F[(size_t)csr[e + 1] * 4 + f8];
            uint4 uc = F[(size_t)csr[e + 2] * 4 + f8];
            uint4 ud = F[(size_t)csr[e + 3] * 4 + f8];
            unpack8(ua, tmp);
#pragma unroll
            for (int j = 0; j < 8; ++j) s[j] += tmp[j];
            unpack8(ub, tmp);
#pragma unroll
            for (int j = 0; j < 8; ++j) s[j] += tmp[j];
            unpack8(uc, tmp);
#pragma unroll
            for (int j = 0; j < 8; ++j) s[j] += tmp[j];
            unpack8(ud, tmp);
#pragma unroll
            for (int j = 0; j < 8; ++j) s[j] += tmp[j];
        }
        for (; e < end; ++e) {
            unpack8(F[(size_t)csr[e] * 4 + f8], tmp);
#pragma unroll
            for (int j = 0; j < 8; ++j) s[j] += tmp[j];
        }
        float dv = dinv[v];
#pragma unroll
        for (int j = 0; j < 8; ++j) a2s[nl * 33 + f8 * 8 + j] = s[j] * dv;
    }
    __syncthreads();

    // phase B: each thread computes 10 classes for its node
    int q = f8;              // classes q*10 .. q*10+9
    float lg[10];
#pragma unroll
    for (int c = 0; c < 10; ++c) lg[c] = b2s[q * 10 + c];
#pragma unroll
    for (int k = 0; k < DIM; ++k) {
        float a = a2s[nl * 33 + k];
        const float* wr = &w2s[k * NCLS + q * 10];
#pragma unroll
        for (int c = 0; c < 10; ++c) lg[c] += a * wr[c];
    }
    float m = lg[0];
#pragma unroll
    for (int c = 1; c < 10; ++c) m = fmaxf(m, lg[c]);
    m = fmaxf(m, __shfl_xor(m, 1));
    m = fmaxf(m, __shfl_xor(m, 2));
    float ssum = 0.f;
#pragma unroll
    for (int c = 0; c < 10; ++c) ssum += __expf(lg[c] - m);
    ssum += __shfl_xor(ssum, 1);
    ssum += __shfl_xor(ssum, 2);
    float lse = m + __logf(ssum);
    if (v < n) {
        float* o = out + (size_t)v * NCLS + q * 10;
#pragma unroll
        for (int c = 0; c < 10; ++c) o[c] = lg[c] - lse;
    }
}

// ---------------------------------------------------------------------------
extern "C" void kernel_launch(void* const* d_in, const int* in_sizes, int n_in,
                              void* d_out, int out_size, void* d_ws, size_t ws_size,
                              hipStream_t stream) {
    const float* x  = (const float*)d_in[0];
    const int*   ei = (const int*)d_in[1];
    const float* W1 = (const float*)d_in[2];
    const float* b1 = (const float*)d_in[3];
    const float* W2 = (const float*)d_in[4];
    const float* b2 = (const float*)d_in[5];
    float* out = (float*)d_out;

    int n = in_sizes[0] / F_IN;   // 100000
    int E = in_sizes[1] / 2;      // 3200000
    const int* src = ei;
    const int* dst = ei + E;
    int nbk = (n + 255) >> BSH;   // 391 (<=512)

    // workspace layout (256B aligned)
    char* w = (char*)d_ws;
    size_t off = 0;
    auto alloc = [&](size_t bytes) -> void* {
        void* p = w + off;
        off += (bytes + 255) & ~(size_t)255;
        return p;
    };
    size_t featB2 = ((size_t)n * DIM * 2 + 255) & ~(size_t)255;  // 6.4 MB bf16
    int*   csr    = (int*)alloc((size_t)E * 4);    // 12.8 MB
    char*  pairsR = (char*)alloc((size_t)E * 4);   // 12.8 MB (aliased below)
    int*   rowptr = (int*)alloc((size_t)(n + 1) * 4);
    float* dinv   = (float*)alloc((size_t)n * 4);
    int*   gh     = (int*)alloc(512 * 4);
    int*   bbase  = (int*)alloc(513 * 4);
    int*   gcur   = (int*)alloc(512 * 4);
    (void)ws_size;

    int*            pairs = (int*)pairsR;                // live: K3..K4
    unsigned short* xwp   = (unsigned short*)pairsR;     // live: gemm1..agg1
    unsigned short* hts   = (unsigned short*)(pairsR + featB2); // live: agg1..agg2

    hipMemsetAsync(gh, 0, 512 * 4, stream);

    int nebk = (E + EPB - 1) / EPB;   // 391
    hist_k <<<nebk, 256, 0, stream>>>(dst, gh, E, nbk);
    scanb_k<<<1, 512, 0, stream>>>(gh, bbase, gcur, nbk);
    part_k <<<nebk, 256, 0, stream>>>(src, dst, gcur, pairs, E);
    build_k<<<nbk, 256, 0, stream>>>(pairs, bbase, rowptr, csr, dinv, n, nbk, E);

    gemm1_k<<<(n + GR - 1) / GR, 256, 0, stream>>>(x, W1, dinv, xwp, n);
    agg1_k<<<((size_t)n * 4 + 255) / 256, 256, 0, stream>>>(
        (const uint4*)xwp, rowptr, csr, dinv, b1, (uint4*)hts, n);
    agg2final_k<<<(n + 63) / 64, 256, 0, stream>>>(
        (const uint4*)hts, rowptr, csr, dinv, W2, b2, out, n);
}